// Round 1
// 193.635 us; speedup vs baseline: 1.0582x; 1.0582x over previous
//
#include <hip/hip_runtime.h>
#include <hip/hip_bf16.h>

#define B_   4
#define S_   8192
#define D_   512
#define DFF_ 2048
#define K_TOP 1024

typedef unsigned short u16;
typedef __attribute__((ext_vector_type(8))) short bf16x8;
typedef __attribute__((ext_vector_type(4))) float floatx4;

// monotonic float -> uint key (order-preserving)
__device__ __forceinline__ unsigned f2key(float f){
    unsigned u = __float_as_uint(f);
    return (u & 0x80000000u) ? ~u : (u | 0x80000000u);
}
// fp32 -> bf16 round-to-nearest-even
__device__ __forceinline__ u16 f2b(float f){
    unsigned u = __float_as_uint(f);
    u = (u + 0x7FFFu + ((u >> 16) & 1u)) >> 16;
    return (u16)u;
}
// fast tanh-gelu via v_exp_f32
__device__ __forceinline__ float gelu_fast(float v){
    float u = 1.5957691216f * v + 0.0713548162726f * v * v * v;
    float e = __expf(u);
    return v - v / (e + 1.0f);
}
// async global->LDS, 16B per lane (wave-uniform base + lane*16)
__device__ __forceinline__ void gl_lds16(const void* gptr, void* lptr){
    auto g = (const __attribute__((address_space(1))) unsigned int*)((uintptr_t)gptr);
    auto l = (__attribute__((address_space(3))) unsigned int*)((uintptr_t)lptr);
    __builtin_amdgcn_global_load_lds(g, l, 16, 0, 0);
}

// All GEMM operand tiles: [tile][kstep128][128 rows][16 chunks of 16B] bf16,
// chunk c of row r stored at slot (c ^ (r&15)) -> conflict-free ds_read_b128.
// BK=64 staging reads half the chunks; since the swizzle factors as
// pg = p | (((h ^ (r>>3)) & 1) << 3), the per-lane GLOBAL address absorbs the
// swizzle and the LDS destination stays linear (global_load_lds requirement).

// ---------------- kernel 1: fused prep -------------------------------------
// blocks [0,64):   W1 fp32 -> W1t tiles      (ct = b&15, ks = b>>4)
// blocks [64,128): W2 fp32 -> W2t tiles      (ct = b&3,  ks = b>>2)
// blocks [128,640): router weights + x->out copy + per-block top-byte hist
__global__ __launch_bounds__(256) void prep_kernel(
    const float* __restrict__ W1, const float* __restrict__ W2,
    u16* __restrict__ W1t, u16* __restrict__ W2t,
    const float4* __restrict__ x, float4* __restrict__ out,
    const float4* __restrict__ Wr4, const float* __restrict__ br,
    float* __restrict__ w_all, unsigned* __restrict__ ghist)
{
    __shared__ __align__(16) unsigned char shmem[128 * 132 * 2]; // 33 KB union
    const int tid = threadIdx.x;
    const int bx = blockIdx.x;
    if (bx < 128){
        const float* src; u16* dst; int R, C, ct, ks;
        if (bx < 64){ src = W1; dst = W1t; R = D_;   C = DFF_; ct = bx & 15;        ks = bx >> 4; }
        else        { src = W2; dst = W2t; R = DFF_; C = D_;   ct = (bx - 64) & 3;  ks = (bx - 64) >> 2; }
        u16 (*tile)[132] = (u16(*)[132])shmem;
        #pragma unroll
        for (int it = 0; it < 64; it++){
            int lin = it * 256 + tid;
            int kk = lin >> 7, nn = lin & 127;
            tile[kk][nn] = f2b(src[(size_t)(ks * 128 + kk) * C + ct * 128 + nn]);
        }
        __syncthreads();
        u16* base = dst + (size_t)(ct * (R / 128) + ks) * 16384;
        const int r = tid >> 1, h = tid & 1;
        #pragma unroll
        for (int c = 0; c < 8; c++){
            int cl = h * 8 + c;
            bf16x8 bv;
            #pragma unroll
            for (int e = 0; e < 8; e++) bv[e] = (short)tile[cl * 8 + e][r];
            *(bf16x8*)&base[r * 128 + ((cl ^ (r & 15)) << 3)] = bv;
        }
    } else {
        unsigned* hist = (unsigned*)shmem;
        if (tid < 256) hist[tid] = 0u;
        __syncthreads();
        const int wb = bx - 128;                  // 0..511, 128 blocks/batch
        const int wv = tid >> 6, lane = tid & 63;
        const int t0 = wb * 64 + wv * 16;
        const float brv = br[0];
        #pragma unroll 2
        for (int tk = 0; tk < 16; tk++){
            int token = t0 + tk;
            const float4* xt = x + (size_t)token * 128;
            float4* ot = out + (size_t)token * 128;
            float acc = 0.f;
            #pragma unroll
            for (int i = 0; i < 2; i++){
                int j = lane + i * 64;
                float4 v = xt[j];
                ot[j] = v;
                float4 wv4 = Wr4[j];
                acc += v.x*wv4.x + v.y*wv4.y + v.z*wv4.z + v.w*wv4.w;
            }
            #pragma unroll
            for (int off = 32; off > 0; off >>= 1) acc += __shfl_down(acc, off, 64);
            if (lane == 0){
                float wt = acc + brv;
                w_all[token] = wt;
                atomicAdd(&hist[f2key(wt) >> 24], 1u);
            }
        }
        __syncthreads();
        if (tid < 256) ghist[wb * 256 + tid] = hist[tid];   // non-atomic row
    }
}

// ------- kernel 2: exact k-th largest per batch (coarse pass precomputed) --
__global__ __launch_bounds__(1024) void kth_compact_kernel(
    const float4* __restrict__ w_all4, const unsigned* __restrict__ ghist,
    int* __restrict__ counts, int* __restrict__ idx)
{
    __shared__ unsigned keys[S_];
    __shared__ unsigned hist[16][256];
    __shared__ unsigned suffix[256];
    __shared__ unsigned sprefix;
    __shared__ int sremk;
    __shared__ int lbase;
    const int b = blockIdx.x, tid = threadIdx.x, wv = tid >> 6;
    const float4* row4 = w_all4 + (size_t)b * (S_ / 4);

    #pragma unroll
    for (int i = 0; i < 2; i++){
        int j = tid + i * 1024;
        float4 v = row4[j];
        keys[4*j+0] = f2key(v.x); keys[4*j+1] = f2key(v.y);
        keys[4*j+2] = f2key(v.z); keys[4*j+3] = f2key(v.w);
    }
    // coarse (top-byte) histogram: sum this batch's 128 prep-block rows
    if (tid < 256){
        unsigned s = 0;
        const unsigned* gh = ghist + (size_t)(b * 128) * 256 + tid;
        #pragma unroll 8
        for (int j = 0; j < 128; j++) s += gh[j * 256];
        suffix[tid] = s;
    }
    if (tid == 0) lbase = 0;
    __syncthreads();
    for (int off = 1; off < 256; off <<= 1){
        unsigned v = 0;
        if (tid < 256 && tid + off < 256) v = suffix[tid + off];
        __syncthreads();
        if (tid < 256) suffix[tid] += v;
        __syncthreads();
    }
    if (tid < 256){
        unsigned snext = (tid == 255) ? 0u : suffix[tid + 1];
        if (suffix[tid] >= (unsigned)K_TOP && snext < (unsigned)K_TOP){
            sprefix = ((unsigned)tid) << 24;
            sremk = K_TOP - (int)snext;
        }
    }
    __syncthreads();

    for (int pass = 2; pass >= 0; pass--){
        for (int i = tid; i < 16 * 256; i += 1024) ((unsigned*)hist)[i] = 0u;
        __syncthreads();
        const unsigned mask_hi = 0xFFFFFFFFu << ((pass + 1) * 8);
        const unsigned pfx = sprefix;
        const int shift = pass * 8;
        #pragma unroll
        for (int i = 0; i < 8; i++){
            unsigned key = keys[tid + i * 1024];
            if ((key & mask_hi) == pfx)
                atomicAdd(&hist[wv][(key >> shift) & 255u], 1u);
        }
        __syncthreads();
        if (tid < 256){
            unsigned s = 0;
            #pragma unroll
            for (int h = 0; h < 16; h++) s += hist[h][tid];
            suffix[tid] = s;
        }
        __syncthreads();
        for (int off = 1; off < 256; off <<= 1){
            unsigned v = 0;
            if (tid < 256 && tid + off < 256) v = suffix[tid + off];
            __syncthreads();
            if (tid < 256) suffix[tid] += v;
            __syncthreads();
        }
        const int remk = sremk;
        __syncthreads();
        if (tid < 256){
            unsigned snext = (tid == 255) ? 0u : suffix[tid + 1];
            if (suffix[tid] >= (unsigned)remk && snext < (unsigned)remk){
                sprefix = pfx | ((unsigned)tid << shift);
                sremk = remk - (int)snext;
            }
        }
        __syncthreads();
    }

    // ballot compaction into per-batch segment idx[b*1024 ..]
    const unsigned thr = sprefix;
    #pragma unroll
    for (int i = 0; i < 8; i++){
        int li = tid + i * 1024;
        bool sel = keys[li] > thr;
        unsigned long long m = __ballot(sel);
        int wtot = (int)__popcll(m);
        if (wtot){
            int woff = 0;
            if ((tid & 63) == 0) woff = atomicAdd(&lbase, wtot);
            woff = __shfl(woff, 0, 64);
            if (sel){
                int pos = woff + (int)__popcll(m & ((1ull << (tid & 63)) - 1ull));
                idx[b * 1024 + pos] = b * S_ + li;
            }
        }
    }
    __syncthreads();
    if (tid == 0) counts[b] = lbase;
}

// --- kernel 3: gather selected x rows -> bf16 tiled+swizzled ---------------
__global__ __launch_bounds__(256) void gather_kernel(
    const float* __restrict__ x, const int* __restrict__ idx,
    const int* __restrict__ counts, u16* __restrict__ XbT)
{
    const int mt = blockIdx.x, s = blockIdx.y;
    const int cl = threadIdx.x & 15, r16 = threadIdx.x >> 4;
    u16* base = XbT + (size_t)(mt * 4 + s) * 16384;
    #pragma unroll
    for (int it = 0; it < 8; it++){
        int r = r16 + it * 16;
        int mg = mt * 128 + r;
        if ((mg & 1023) < counts[mg >> 10]){
            const float* xp = x + (size_t)idx[mg] * D_ + s * 128 + cl * 8;
            float4 v0 = *(const float4*)xp;
            float4 v1 = *(const float4*)(xp + 4);
            bf16x8 bv;
            bv[0]=(short)f2b(v0.x); bv[1]=(short)f2b(v0.y);
            bv[2]=(short)f2b(v0.z); bv[3]=(short)f2b(v0.w);
            bv[4]=(short)f2b(v1.x); bv[5]=(short)f2b(v1.y);
            bv[6]=(short)f2b(v1.z); bv[7]=(short)f2b(v1.w);
            *(bf16x8*)&base[r * 128 + ((cl ^ (r & 15)) << 3)] = bv;
        }
    }
}

// --- kernel 4: GEMM1  Ht = gelu(Xsel @ W1 + b1), 128x128 tile, BK=64 dbuf --
// LDS 64 KB -> 2 blocks/CU
__global__ __launch_bounds__(256) void ffn1_kernel(
    const u16* __restrict__ XbT, const u16* __restrict__ W1t,
    const int* __restrict__ counts, const float* __restrict__ bias1,
    u16* __restrict__ Ht)
{
    __shared__ __align__(16) u16 smem[32768];     // A:2x16KB | B:2x16KB
    const int tid = threadIdx.x;
    const int mBlk = blockIdx.x, nBlk = blockIdx.y;
    const int lane = tid & 63, w = tid >> 6;
    const int wr = (w >> 1) * 64, wc = (w & 1) * 64;
    const int fr = lane & 15, quad = lane >> 4;

    const char* Abase = (const char*)(XbT + (size_t)mBlk * 4 * 16384);
    const char* Bbase = (const char*)(W1t + (size_t)nBlk * 4 * 16384);
    char* Al0 = (char*)smem + tid * 16;
    char* Bl0 = (char*)(smem + 16384) + tid * 16;
    const int rr0 = tid >> 3, pp = tid & 7;

    auto stage = [&](const char* gbase, char* lb, int hs){
        const char* s0 = gbase + (size_t)(hs >> 1) * 32768;
        const int h = hs & 1;
        #pragma unroll
        for (int i = 0; i < 4; i++){
            int r = rr0 + i * 32;
            int pg = pp | (((h ^ (r >> 3)) & 1) << 3);
            gl_lds16(s0 + r * 256 + pg * 16, lb + i * 4096);
        }
    };

    stage(Abase, Al0, 0);
    stage(Bbase, Bl0, 0);

    floatx4 acc[4][4] = {};
    for (int hs = 0; hs < 8; hs++){
        __syncthreads();
        if (hs + 1 < 8){
            stage(Abase, Al0 + ((hs + 1) & 1) * 16384, hs + 1);
            stage(Bbase, Bl0 + ((hs + 1) & 1) * 16384, hs + 1);
        }
        const u16* Ab = smem + (hs & 1) * 8192;
        const u16* Bb = smem + 16384 + (hs & 1) * 8192;
        #pragma unroll
        for (int ks2 = 0; ks2 < 2; ks2++){
            bf16x8 af[4], bf[4];
            #pragma unroll
            for (int i = 0; i < 4; i++){
                int r = wr + i * 16 + fr;
                af[i] = *(const bf16x8*)&Ab[r * 64 + (((ks2 * 4 + quad) ^ (r & 7)) << 3)];
            }
            #pragma unroll
            for (int j = 0; j < 4; j++){
                int r = wc + j * 16 + fr;
                bf[j] = *(const bf16x8*)&Bb[r * 64 + (((ks2 * 4 + quad) ^ (r & 7)) << 3)];
            }
            #pragma unroll
            for (int i = 0; i < 4; i++)
                #pragma unroll
                for (int j = 0; j < 4; j++)
                    acc[i][j] = __builtin_amdgcn_mfma_f32_16x16x32_bf16(af[i], bf[j], acc[i][j], 0, 0, 0);
        }
    }

    float bj[4];
    #pragma unroll
    for (int j = 0; j < 4; j++) bj[j] = bias1[nBlk * 128 + wc + j * 16 + fr];

    __syncthreads();
    u16* Cs = smem;                  // 32KB: [128 r][128 c] swizzled
    #pragma unroll
    for (int i = 0; i < 4; i++){
        #pragma unroll
        for (int rg = 0; rg < 4; rg++){
            int r = wr + i * 16 + quad * 4 + rg;
            #pragma unroll
            for (int j = 0; j < 4; j++){
                int col = wc + j * 16 + fr;
                float v = gelu_fast(acc[i][j][rg] + bj[j]);
                Cs[r * 128 + ((((col >> 3) ^ (r & 15)) << 3) | (col & 7))] = f2b(v);
            }
        }
    }
    __syncthreads();
    const int r = tid >> 1, h = tid & 1;
    int mg = mBlk * 128 + r;
    if ((mg & 1023) < counts[mg >> 10]){
        u16* dstp = Ht + (((size_t)(mBlk * 2 + (r >> 6)) * 16 + nBlk) * 64 + (r & 63)) * 128;
        #pragma unroll
        for (int p = 0; p < 8; p++){
            int pc = h * 8 + p;
            *(bf16x8*)&dstp[pc << 3] = *(const bf16x8*)&Cs[r * 128 + (pc << 3)];
        }
    }
}

// --- kernel 5: GEMM2  out[token] = (H @ W2 + b2) * w, 64x128 tile, BK=64 ---
// LDS 48 KB -> 3 blocks/CU
__global__ __launch_bounds__(256) void ffn2_kernel(
    const u16* __restrict__ Ht, const u16* __restrict__ W2t,
    const int* __restrict__ counts, const int* __restrict__ idx,
    const float* __restrict__ w_all, const float* __restrict__ bias2,
    float* __restrict__ out)
{
    __shared__ __align__(16) u16 smem[24576];     // A:2x8KB | B:2x16KB
    const int tid = threadIdx.x;
    const int mBlk = blockIdx.x, nBlk = blockIdx.y;
    const int lane = tid & 63, w = tid >> 6;
    const int wr = (w >> 1) * 32, wc = (w & 1) * 64;
    const int fr = lane & 15, quad = lane >> 4;

    const char* Abase = (const char*)(Ht + (size_t)mBlk * 16 * 8192);
    const char* Bbase = (const char*)(W2t + (size_t)nBlk * 16 * 16384);
    char* Al0 = (char*)smem + tid * 16;
    char* Bl0 = (char*)(smem + 8192) + tid * 16;
    const int rr0 = tid >> 3, pp = tid & 7;

    auto stageA = [&](int buf, int hs){
        const char* s0 = Abase + (size_t)(hs >> 1) * 16384;
        const int h = hs & 1;
        char* l = Al0 + buf * 8192;
        #pragma unroll
        for (int i = 0; i < 2; i++){
            int r = rr0 + i * 32;
            int pg = pp | (((h ^ (r >> 3)) & 1) << 3);
            gl_lds16(s0 + r * 256 + pg * 16, l + i * 4096);
        }
    };
    auto stageB = [&](int buf, int hs){
        const char* s0 = Bbase + (size_t)(hs >> 1) * 32768;
        const int h = hs & 1;
        char* l = Bl0 + buf * 16384;
        #pragma unroll
        for (int i = 0; i < 4; i++){
            int r = rr0 + i * 32;
            int pg = pp | (((h ^ (r >> 3)) & 1) << 3);
            gl_lds16(s0 + r * 256 + pg * 16, l + i * 4096);
        }
    };

    stageA(0, 0); stageB(0, 0);
    floatx4 acc[2][4] = {};
    for (int hs = 0; hs < 32; hs++){
        __syncthreads();
        if (hs + 1 < 32){ stageA((hs + 1) & 1, hs + 1); stageB((hs + 1) & 1, hs + 1); }
        const u16* Ab = smem + (hs & 1) * 4096;
        const u16* Bb = smem + 8192 + (hs & 1) * 8192;
        #pragma unroll
        for (int ks2 = 0; ks2 < 2; ks2++){
            bf16x8 af[2], bf[4];
            #pragma unroll
            for (int i = 0; i < 2; i++){
                int r = wr + i * 16 + fr;
                af[i] = *(const bf16x8*)&Ab[r * 64 + (((ks2 * 4 + quad) ^ (r & 7)) << 3)];
            }
            #pragma unroll
            for (int j = 0; j < 4; j++){
                int r = wc + j * 16 + fr;
                bf[j] = *(const bf16x8*)&Bb[r * 64 + (((ks2 * 4 + quad) ^ (r & 7)) << 3)];
            }
            #pragma unroll
            for (int i = 0; i < 2; i++)
                #pragma unroll
                for (int j = 0; j < 4; j++)
                    acc[i][j] = __builtin_amdgcn_mfma_f32_16x16x32_bf16(af[i], bf[j], acc[i][j], 0, 0, 0);
        }
    }

    float bj[4];
    #pragma unroll
    for (int j = 0; j < 4; j++) bj[j] = bias2[nBlk * 128 + wc + j * 16 + fr];

    __syncthreads();
    float* Cs = (float*)smem;        // 32KB: [64 r][128 c]
    #pragma unroll
    for (int i = 0; i < 2; i++){
        #pragma unroll
        for (int rg = 0; rg < 4; rg++){
            int r = wr + i * 16 + quad * 4 + rg;
            #pragma unroll
            for (int j = 0; j < 4; j++)
                Cs[r * 128 + wc + j * 16 + fr] = acc[i][j][rg] + bj[j];
        }
    }
    __syncthreads();
    const int r = tid >> 2, q = tid & 3;
    int mg = mBlk * 64 + r;
    if ((mg & 1023) < counts[mg >> 10]){
        int token = idx[mg];
        float wt = w_all[token];
        float* op = out + (size_t)token * D_ + nBlk * 128 + q * 32;
        const float4* cp = (const float4*)&Cs[r * 128 + q * 32];
        #pragma unroll
        for (int p = 0; p < 8; p++){
            float4 vv = cp[p];
            vv.x *= wt; vv.y *= wt; vv.z *= wt; vv.w *= wt;
            ((float4*)op)[p] = vv;
        }
    }
}

extern "C" void kernel_launch(void* const* d_in, const int* in_sizes, int n_in,
                              void* d_out, int out_size, void* d_ws, size_t ws_size,
                              hipStream_t stream)
{
    const float* x  = (const float*)d_in[0];
    const float* Wr = (const float*)d_in[2];
    const float* br = (const float*)d_in[3];
    const float* W1 = (const float*)d_in[4];
    const float* b1 = (const float*)d_in[5];
    const float* W2 = (const float*)d_in[6];
    const float* b2 = (const float*)d_in[7];
    float* out = (float*)d_out;
    char* ws = (char*)d_ws;

    // workspace layout (bytes)
    float*    w_all  = (float*)   (ws + 0);         // 128 KB
    int*      counts = (int*)     (ws + 131072);    // 16 B (per-batch)
    int*      idx    = (int*)     (ws + 131136);    // 16 KB [4][1024]
    unsigned* ghist  = (unsigned*)(ws + 163840);    // 512 KB [512][256]
    u16*      XbT    = (u16*)     (ws + 720896);    // 4 MB  [32][4][128][128]
    u16*      W1t    = (u16*)     (ws + 4915200);   // 2 MB  [16][4][128][128]
    u16*      W2t    = (u16*)     (ws + 7012352);   // 2 MB  [4][16][128][128]
    u16*      Ht     = (u16*)     (ws + 9109504);   // 16 MB [64][16][64][128]

    prep_kernel<<<640, 256, 0, stream>>>(
        W1, W2, W1t, W2t, (const float4*)x, (float4*)out,
        (const float4*)Wr, br, w_all, ghist);
    kth_compact_kernel<<<B_, 1024, 0, stream>>>(
        (const float4*)w_all, ghist, counts, idx);
    gather_kernel<<<dim3(32, 4), 256, 0, stream>>>(x, idx, counts, XbT);
    ffn1_kernel<<<dim3(32, DFF_/128), 256, 0, stream>>>(XbT, W1t, counts, b1, Ht);
    ffn2_kernel<<<dim3(64, D_/128),   256, 0, stream>>>(Ht, W2t, counts, idx, w_all, b2, out);
}